// Round 5
// baseline (81.208 us; speedup 1.0000x reference)
//
#include <hip/hip_runtime.h>

#define N      4096
#define NNB    4
#define BLOCK  256
#define WAVES_PER_BLOCK 4

__device__ __forceinline__ unsigned long long wave_min_ull(unsigned long long m) {
    #pragma unroll
    for (int off = 32; off > 0; off >>= 1) {
        unsigned long long o = __shfl_xor(m, off, 64);
        m = (o < m) ? o : m;
    }
    return m;
}

// Branchless sorted-insert: keep 4 smallest u64 keys in k0<=k1<=k2<=k3.
__device__ __forceinline__ void insert4(unsigned long long key,
                                        unsigned long long& k0, unsigned long long& k1,
                                        unsigned long long& k2, unsigned long long& k3) {
    unsigned long long t = key, m;
    m = (t < k0) ? t : k0;  t = (t < k0) ? k0 : t;  k0 = m;
    m = (t < k1) ? t : k1;  t = (t < k1) ? k1 : t;  k1 = m;
    m = (t < k2) ? t : k2;  t = (t < k2) ? k2 : t;  k2 = m;
    k3 = (t < k3) ? t : k3;
}

__global__ __launch_bounds__(BLOCK) void knn_pool_kernel(
    const float* __restrict__ obs1,
    const float* __restrict__ obs2,
    const float* __restrict__ W,
    const float* __restrict__ b,
    float* __restrict__ out)
{
    __shared__ __align__(16) float2 s_obs[N];   // 32 KiB: the whole obs2

    const int tid = threadIdx.x;

    // Stage obs2 -> LDS with float4, coalesced.
    {
        const float4* src = (const float4*)obs2;
        float4* dst = (float4*)s_obs;
        #pragma unroll
        for (int t = 0; t < (N * 2 / 4) / BLOCK; ++t)   // 2048/256 = 8
            dst[tid + t * BLOCK] = src[tid + t * BLOCK];
    }
    __syncthreads();

    const int wave = tid >> 6;
    const int lane = tid & 63;
    const int i = blockIdx.x * WAVES_PER_BLOCK + wave;   // this wave's row

    const float2 pi = s_obs[i];

    // ---- per-lane top-4, 2 candidates per ds_read_b128, fully branchless ----
    // key = (bits(dist) << 32) | j : unsigned compare == (dist, index) lexicographic
    unsigned long long k0 = ~0ULL, k1 = ~0ULL, k2 = ~0ULL, k3 = ~0ULL;

    const float4* s4 = (const float4*)s_obs;
    #pragma unroll 4
    for (int jj = 0; jj < N / 128; ++jj) {       // 32 iterations
        const int t  = jj * 64 + lane;           // float4 index
        const float4 q = s4[t];
        const int j0 = 2 * t;
        const int j1 = 2 * t + 1;

        const float dx0 = q.x - pi.x, dy0 = q.y - pi.y;
        const float dx1 = q.z - pi.x, dy1 = q.w - pi.y;
        const float d0 = sqrtf(dx0 * dx0 + dy0 * dy0);
        const float d1 = sqrtf(dx1 * dx1 + dy1 * dy1);

        unsigned long long key0 =
            ((unsigned long long)__float_as_uint(d0) << 32) | (unsigned)j0;
        unsigned long long key1 =
            ((unsigned long long)__float_as_uint(d1) << 32) | (unsigned)j1;
        if (j0 == i) key0 = ~0ULL;               // diagonal -> +inf (excluded)
        if (j1 == i) key1 = ~0ULL;

        insert4(key0, k0, k1, k2, k3);
        insert4(key1, k0, k1, k2, k3);
    }

    // ---- cross-lane merge: 4x (wave-min + pop owner) ----
    // Keys are globally unique (index in low bits) -> exactly one lane pops.
    unsigned long long sel0, sel1, sel2, sel3;
    sel0 = wave_min_ull(k0);
    if (k0 == sel0) { k0 = k1; k1 = k2; k2 = k3; k3 = ~0ULL; }
    sel1 = wave_min_ull(k0);
    if (k0 == sel1) { k0 = k1; k1 = k2; k2 = k3; k3 = ~0ULL; }
    sel2 = wave_min_ull(k0);
    if (k0 == sel2) { k0 = k1; k1 = k2; k2 = k3; k3 = ~0ULL; }
    sel3 = wave_min_ull(k0);

    // ---- epilogue: lanes 0..31 -> one output each (k = lane>>3, o = lane&7) ----
    if (lane < 32) {
        const int k = lane >> 3;
        const int o = lane & 7;
        const unsigned long long sk =
            (k == 0) ? sel0 : (k == 1) ? sel1 : (k == 2) ? sel2 : sel3;
        const int j = (int)(unsigned)(sk & 0xffffffffu);

        const float2 pj  = s_obs[j];
        const float o1ix = obs1[2 * i],  o1iy = obs1[2 * i + 1];
        const float o1jx = obs1[2 * j],  o1jy = obs1[2 * j + 1];

        const float vix = pi.x - o1ix, viy = pi.y - o1iy;   // vel[i]
        const float vjx = pj.x - o1jx, vjy = pj.y - o1jy;   // vel[j]

        const float f0 = pj.x - pi.x;      // rel_pos.x
        const float f1 = pj.y - pi.y;      // rel_pos.y
        const float f2 = vjx - vix;        // rel_vel.x
        const float f3 = vjy - viy;        // rel_vel.y

        float acc = f0 * W[o * 4 + 0];
        acc += f1 * W[o * 4 + 1];
        acc += f2 * W[o * 4 + 2];
        acc += f3 * W[o * 4 + 3];
        acc += b[o];
        out[i * 32 + lane] = fmaxf(acc, 0.0f);
    }
}

extern "C" void kernel_launch(void* const* d_in, const int* in_sizes, int n_in,
                              void* d_out, int out_size, void* d_ws, size_t ws_size,
                              hipStream_t stream) {
    const float* obs1 = (const float*)d_in[0];
    const float* obs2 = (const float*)d_in[1];
    const float* W    = (const float*)d_in[2];
    const float* b    = (const float*)d_in[3];
    float* out = (float*)d_out;

    knn_pool_kernel<<<dim3(N / WAVES_PER_BLOCK), dim3(BLOCK), 0, stream>>>(
        obs1, obs2, W, b, out);
}